// Round 9
// baseline (238.631 us; speedup 1.0000x reference)
//
#include <hip/hip_runtime.h>
#include <hip/hip_bf16.h>
#include <hip/hip_fp16.h>

#define C_DIM 64
#define M_DIM 8
#define O_DIM 64
#define KSLOT 26
#define OVF_CAP 32768

// ---- bucketing parameters ----
#define G1 256      // pass-1 bucket blocks (each takes a contiguous E/G1 chunk)
#define BSHIFT 9    // 512 vertices per bucket
#define NBMAX 208   // max buckets (V <= 106496)
#define CAP_PB 40   // pool records per (bucket, block) private section (320B = 5 lines)

typedef _Float16 h8 __attribute__((ext_vector_type(8)));
typedef float f32x4 __attribute__((ext_vector_type(4)));

union HH { __half2 h2; unsigned int u; _Float16 f2[2]; };

__device__ __forceinline__ unsigned int packh2(float a, float b) {
    HH x;
    x.f2[0] = (_Float16)a;
    x.f2[1] = (_Float16)b;
    return x.u;
}
__device__ __forceinline__ int rfl(int x) { return __builtin_amdgcn_readfirstlane(x); }

// Pass 1 + streaming prep (R8-verified, unchanged):
//  blocks [0, G1): bucket edges by src>>BSHIFT into private per-(bucket,block)
//                  pool sections (L2-resident scatter window per block).
//  blocks [G1, G1+16): repack var_w into MFMA B-fragment order.
//  blocks [G1+16, ...): MERGED data->f16 + xu (butterfly-reduced).
__global__ __launch_bounds__(256) void prep_kernel(
    const float* __restrict__ data, const float* __restrict__ u,
    const int* __restrict__ esrc, const int* __restrict__ edst,
    const float* __restrict__ ew, const float* __restrict__ w,
    _Float16* __restrict__ xuh, unsigned short* __restrict__ datah,
    uint2* __restrict__ pool, int* __restrict__ gpb,
    int* __restrict__ ovf_cnt, uint4* __restrict__ ovf,
    _Float16* __restrict__ bfrag, int V, int E, int nb) {
    __shared__ int fcnt[NBMAX];
    __shared__ float uS[576];  // var_u staged with stride 9 (bank-spread)
    int b = blockIdx.x, t = threadIdx.x;

    if (b < G1) {
        // ---------------- bucketing role ----------------
        for (int i = t; i < NBMAX; i += 256) fcnt[i] = 0;
        __syncthreads();
        int per = (E + G1 - 1) / G1;
        int eBeg = b * per;
        int eEnd = min(E, eBeg + per);
        for (int e = eBeg + t; e < eEnd; e += 256) {
            int s = esrc[e];
            int bk = s >> BSHIFT;
            uint2 rec;
            rec.x = (unsigned int)edst[e] | ((unsigned int)(s & 511) << 17);
            rec.y = __float_as_uint(ew[e]);
            int fr = atomicAdd(&fcnt[bk], 1);
            if (fr < CAP_PB) {
                pool[((size_t)bk * G1 + b) * CAP_PB + fr] = rec;
            } else {
                int oi = atomicAdd(ovf_cnt, 1);
                if (oi < OVF_CAP) {
                    uint4 o4;
                    o4.x = (unsigned int)s;
                    o4.y = rec.x & 0x1FFFFu;
                    o4.z = rec.y;
                    o4.w = 0;
                    ovf[oi] = o4;
                }
            }
        }
        __syncthreads();
        if (t < nb) {
            int fc = fcnt[t];
            gpb[t * G1 + b] = (fc < CAP_PB) ? fc : CAP_PB;
        }
        return;
    }

    if (b < G1 + 16) {
        // ---------------- wb fold role ----------------
        int tt = (b - G1) * 256 + t;
        int kt = tt >> 8;
        int rem = tt & 255;
        int nt = rem >> 6;
        int lane = rem & 63;
        int quad = lane >> 4;
        int n = nt * 16 + (lane & 15);
#pragma unroll
        for (int j = 0; j < 8; ++j) {
            int k = kt * 32 + quad * 8 + j;
            bfrag[(size_t)tt * 8 + j] = (_Float16)w[k * 64 + n];
        }
        return;
    }

    // ---------------- streaming role: data->f16 + fused xu ----------------
    int vb = b - (G1 + 16);
    for (int i = t; i < 512; i += 256) uS[(i >> 3) * 9 + (i & 7)] = u[i];
    __syncthreads();

    size_t base = (size_t)vb * 2048 + (size_t)t * 8;
    float x[8];
    if (base + 7 < (size_t)V * C_DIM) {
        f32x4 x0 = *(const f32x4*)&data[base];
        f32x4 x1 = *(const f32x4*)&data[base + 4];
        uint4 o;
        o.x = packh2(x0[0], x0[1]);
        o.y = packh2(x0[2], x0[3]);
        o.z = packh2(x1[0], x1[1]);
        o.w = packh2(x1[2], x1[3]);
        *(uint4*)&datah[base] = o;
        x[0] = x0[0]; x[1] = x0[1]; x[2] = x0[2]; x[3] = x0[3];
        x[4] = x1[0]; x[5] = x1[1]; x[6] = x1[2]; x[7] = x1[3];
    } else {
#pragma unroll
        for (int i = 0; i < 8; ++i) x[i] = 0.f;
    }
    // per-lane partials over this lane's 8 channels
    int c0 = (t & 7) * 8;
    float p[8];
#pragma unroll
    for (int m = 0; m < 8; ++m) p[m] = 0.f;
#pragma unroll
    for (int i = 0; i < 8; ++i) {
        const float* ur = &uS[(c0 + i) * 9];
#pragma unroll
        for (int m = 0; m < 8; ++m) p[m] = fmaf(x[i], ur[m], p[m]);
    }
    // butterfly-reduce across the 8 lanes of this vertex
#pragma unroll
    for (int d = 1; d < 8; d <<= 1) {
#pragma unroll
        for (int m = 0; m < 8; ++m) p[m] += __shfl_xor(p[m], d, 64);
    }
    int v = vb * 32 + (t >> 3);
    if (v < V) {
        int mi = t & 7;
        float outv = p[0];
#pragma unroll
        for (int m = 1; m < 8; ++m) if (mi == m) outv = p[m];
        xuh[(size_t)v * 8 + mi] = (_Float16)outv;
    }
}

// Pass 2 (R6-verified, unchanged): one block (512 threads) per 512-vertex
// bucket; whole 80KB pool slice in LDS; 2 threads split each section's slots.
__global__ __launch_bounds__(512) void place_kernel(
    const uint2* __restrict__ pool, const int* __restrict__ gpb,
    unsigned int* __restrict__ recs, int* __restrict__ counts,
    int* __restrict__ ovf_cnt, uint4* __restrict__ ovf, int V) {
    __shared__ uint2 lpool[G1 * CAP_PB];  // 256*40*8 = 80 KB
    __shared__ int vcnt[512];
    __shared__ int cnts[G1];
    int b = blockIdx.x, t = threadIdx.x;
    vcnt[t] = 0;
    if (t < G1) cnts[t] = gpb[b * G1 + t];
    const uint4* src = (const uint4*)&pool[(size_t)b * G1 * CAP_PB];
    uint4* dst4 = (uint4*)lpool;
#pragma unroll
    for (int k = 0; k < G1 * CAP_PB / 2 / 512; ++k) {
        dst4[k * 512 + t] = src[k * 512 + t];
    }
    __syncthreads();

    {
        int sec = t >> 1;
        int half = t & 1;
        int cnt = cnts[sec];
        if (cnt > CAP_PB) cnt = CAP_PB;
        if (cnt < 0) cnt = 0;
        int lo = half * (CAP_PB / 2);
        int hi = half ? cnt : min(cnt, CAP_PB / 2);
        int basei = sec * CAP_PB;
        for (int k = lo; k < hi; ++k) {
            uint2 rec = lpool[basei + k];
            int low = (int)(rec.x >> 17);
            int dst = (int)(rec.x & 0x1FFFFu);
            int r = atomicAdd(&vcnt[low], 1);
            int v = (b << BSHIFT) + low;
            if (r < KSLOT) {
                HH wh;
                wh.f2[0] = (_Float16)__uint_as_float(rec.y);
                unsigned int wf = wh.u & 0xFFFFu;  // sign bit 0 (w >= 0)
                recs[(size_t)v * KSLOT + r] = (unsigned int)dst | (wf << 17);
            } else {
                int oi = atomicAdd(ovf_cnt, 1);
                if (oi < OVF_CAP) {
                    uint4 o4;
                    o4.x = (unsigned int)v;
                    o4.y = (unsigned int)dst;
                    o4.z = rec.y;
                    o4.w = 0;
                    ovf[oi] = o4;
                }
            }
        }
    }
    __syncthreads();
    int v0 = (b << BSHIFT) + t;
    if (v0 < V) counts[v0] = vcnt[t] < KSLOT ? vcnt[t] : KSLOT;
}

// Fused: R8 body, now GRID-STRIDED over tiles (1792 persistent blocks):
// amortizes per-block dispatch churn ~3.5x. All LDS except At is per-wave;
// one extra barrier at tile-loop end guards At (epilogue-read of tile t vs
// deposit-write of tile t+1).
#define A_STRIDE 520
__global__ __launch_bounds__(256) void fused_kernel(
    const unsigned short* __restrict__ datah, const unsigned int* __restrict__ recs,
    const _Float16* __restrict__ xuh, const float* __restrict__ vc,
    const int* __restrict__ counts, const _Float16* __restrict__ bfragG,
    const float* __restrict__ bias, float* __restrict__ out, int V, int ntiles) {
    __shared__ _Float16 At[16 * A_STRIDE];
    __shared__ int ebj[4][64];
    __shared__ uint4 ebq[4][64];
    __shared__ float xscS[4][4][8];
    __shared__ int pS[4][5];
    __shared__ int oS[4][4];
    int wave = rfl(threadIdx.x >> 6);
    int lane = threadIdx.x & 63;

    for (int tile = blockIdx.x; tile < ntiles; tile += gridDim.x) {
        int v_base = tile * 16;
        int v0 = v_base + wave * 4;

        if (lane < 4) {
            int v = v0 + lane;
            int dd = (v < V) ? min(counts[v], KSLOT) : 0;
            oS[wave][lane] = v * KSLOT;
            pS[wave][lane + 1] = dd;
        }
        if (lane == 0) {
            pS[wave][0] = 0;
            int s = 0;
#pragma unroll
            for (int i = 1; i <= 4; ++i) {
                s += pS[wave][i];
                pS[wave][i] = s;
            }
        }
        if (lane < 32) {
            int i = lane >> 3, m = lane & 7;
            int v = v0 + i;
            float s = 0.f;
            if (v < V) s = (float)xuh[(size_t)v0 * 8 + lane] + vc[m];
            xscS[wave][i][m] = s;
        }

        HH z; z.u = 0;
        __half2 acc[4][4];
#pragma unroll
        for (int i = 0; i < 4; ++i)
#pragma unroll
            for (int k = 0; k < 4; ++k) acc[i][k] = z.h2;

        int total = rfl(pS[wave][4]);

        for (int c0 = 0; c0 < total; c0 += 64) {
            // ---- Phase A: one edge per lane across the wave's 4 rows ----
            int g = c0 + lane;
            if (g < total) {
                int p1 = pS[wave][1], p2 = pS[wave][2], p3 = pS[wave][3];
                int r = (g >= p1) + (g >= p2) + (g >= p3);
                int pr = (r > 0) ? ((r > 1) ? ((r > 2) ? p3 : p2) : p1) : 0;
                int ob = oS[wave][r];
                int pos = ob + (g - pr);
                unsigned int rec = recs[pos];
                int j = (int)(rec & 0x1FFFFu);
                HH wh; wh.u = rec >> 17;
                float w = (float)wh.f2[0];
                f32x4 xa = *(const f32x4*)&xscS[wave][r][0];
                f32x4 xb = *(const f32x4*)&xscS[wave][r][4];
                uint4 xr = *(const uint4*)&xuh[(size_t)j * 8];
                HH a2, b2, c2, d2;
                a2.u = xr.x; b2.u = xr.y; c2.u = xr.z; d2.u = xr.w;
                float lg[8];
                lg[0] = xa[0] - (float)a2.f2[0];
                lg[1] = xa[1] - (float)a2.f2[1];
                lg[2] = xa[2] - (float)b2.f2[0];
                lg[3] = xa[3] - (float)b2.f2[1];
                lg[4] = xb[0] - (float)c2.f2[0];
                lg[5] = xb[1] - (float)c2.f2[1];
                lg[6] = xb[2] - (float)d2.f2[0];
                lg[7] = xb[3] - (float)d2.f2[1];
                float mx = -1e30f;
#pragma unroll
                for (int m = 0; m < 8; ++m) mx = fmaxf(mx, lg[m]);
                float den = 0.f;
#pragma unroll
                for (int m = 0; m < 8; ++m) {
                    lg[m] = __expf(lg[m] - mx);
                    den += lg[m];
                }
                float inv = w / den;
#pragma unroll
                for (int m = 0; m < 8; ++m) lg[m] *= inv;
                uint4 qp;
                qp.x = packh2(lg[0], lg[1]);
                qp.y = packh2(lg[2], lg[3]);
                qp.z = packh2(lg[4], lg[5]);
                qp.w = packh2(lg[6], lg[7]);
                ebj[wave][lane] = j;
                ebq[wave][lane] = qp;
            }
            // ---- Phase B: consume, row by row (same wave, 8-deep MLP) ----
#define CONSUME2(rr, qv, xsv)                                                  \
    do {                                                                       \
        HH q01, q23, q45, q67, xx;                                             \
        q01.u = (qv).x; q23.u = (qv).y;                                        \
        q45.u = (qv).z; q67.u = (qv).w;                                        \
        unsigned int xv_ = (unsigned int)(xsv);                                \
        xx.u = xv_ | (xv_ << 16);                                              \
        acc[rr][0] = __hfma2(xx.h2, q01.h2, acc[rr][0]);                       \
        acc[rr][1] = __hfma2(xx.h2, q23.h2, acc[rr][1]);                       \
        acc[rr][2] = __hfma2(xx.h2, q45.h2, acc[rr][2]);                       \
        acc[rr][3] = __hfma2(xx.h2, q67.h2, acc[rr][3]);                       \
    } while (0)
#pragma unroll
            for (int r2 = 0; r2 < 4; ++r2) {
                int pr0 = rfl(pS[wave][r2]);
                int pr1 = rfl(pS[wave][r2 + 1]);
                int lo2 = max(pr0, c0);
                int hi2 = min(pr1, c0 + 64);
                int n = hi2 - lo2;
                if (n <= 0) continue;
                int tb = lo2 - c0;
                int tt = 0;
                for (; tt + 8 <= n; tt += 8) {
                    int jj[8];
                    uint4 qq[8];
                    unsigned short xs[8];
#pragma unroll
                    for (int u = 0; u < 8; ++u) {
                        jj[u] = rfl(ebj[wave][tb + tt + u]);
                        qq[u] = ebq[wave][tb + tt + u];
                    }
#pragma unroll
                    for (int u = 0; u < 8; ++u) {
                        const unsigned short* xp = datah + ((size_t)jj[u] << 6);
                        xs[u] = xp[lane];
                    }
#pragma unroll
                    for (int u = 0; u < 8; ++u) CONSUME2(r2, qq[u], xs[u]);
                }
                for (; tt + 4 <= n; tt += 4) {
                    int jj[4];
                    uint4 qq[4];
                    unsigned short xs[4];
#pragma unroll
                    for (int u = 0; u < 4; ++u) {
                        jj[u] = rfl(ebj[wave][tb + tt + u]);
                        qq[u] = ebq[wave][tb + tt + u];
                    }
#pragma unroll
                    for (int u = 0; u < 4; ++u) {
                        const unsigned short* xp = datah + ((size_t)jj[u] << 6);
                        xs[u] = xp[lane];
                    }
#pragma unroll
                    for (int u = 0; u < 4; ++u) CONSUME2(r2, qq[u], xs[u]);
                }
                for (; tt < n; ++tt) {
                    int j0 = rfl(ebj[wave][tb + tt]);
                    uint4 qv = ebq[wave][tb + tt];
                    const unsigned short* xp = datah + ((size_t)j0 << 6);
                    unsigned short xs0 = xp[lane];
                    CONSUME2(r2, qv, xs0);
                }
            }
        }

        // Deposit A-tile rows
#pragma unroll
        for (int i = 0; i < 4; ++i) {
            int row = wave * 4 + i;
            HH a01, a23, a45, a67;
            a01.h2 = acc[i][0]; a23.h2 = acc[i][1];
            a45.h2 = acc[i][2]; a67.h2 = acc[i][3];
            _Float16* Ar = &At[row * A_STRIDE + lane];
            Ar[0 * 64] = a01.f2[0];
            Ar[1 * 64] = a01.f2[1];
            Ar[2 * 64] = a23.f2[0];
            Ar[3 * 64] = a23.f2[1];
            Ar[4 * 64] = a45.f2[0];
            Ar[5 * 64] = a45.f2[1];
            Ar[6 * 64] = a67.f2[0];
            Ar[7 * 64] = a67.f2[1];
        }
        __syncthreads();

        // MFMA epilogue: wave = output column tile
        f32x4 cacc = {0.f, 0.f, 0.f, 0.f};
        int quad = lane >> 4;
        int r16 = lane & 15;
#pragma unroll
        for (int kt = 0; kt < 16; ++kt) {
            h8 a = *(const h8*)&At[r16 * A_STRIDE + kt * 32 + quad * 8];
            h8 b = *(const h8*)&bfragG[((size_t)(kt * 4 + wave) * 64 + lane) * 8];
            cacc = __builtin_amdgcn_mfma_f32_16x16x32_f16(a, b, cacc, 0, 0, 0);
        }
#pragma unroll
        for (int r = 0; r < 4; ++r) {
            int row = quad * 4 + r;
            int v = v_base + row;
            if (v < V) {
                int o = wave * 16 + r16;
                out[(size_t)v * 64 + o] = cacc[r] + bias[o];
            }
        }
        __syncthreads();  // At reuse guard: epilogue-read done before next deposit
    }
}

// Exact handling of overflow records {src, dst, w(f32)} (unchanged).
__global__ __launch_bounds__(256) void cleanup_kernel(
    const int* __restrict__ ovf_cnt, const uint4* __restrict__ ovf,
    const _Float16* __restrict__ xuh, const float* __restrict__ vc,
    const float* __restrict__ var_w, const unsigned short* __restrict__ datah,
    float* __restrict__ out) {
    int n = min(*ovf_cnt, OVF_CAP);
    int nw = gridDim.x * (blockDim.x >> 6);
    int wid = blockIdx.x * (blockDim.x >> 6) + (threadIdx.x >> 6);
    int lane = threadIdx.x & 63;
    for (int i = wid; i < n; i += nw) {
        uint4 r4 = ovf[i];
        int s = (int)r4.x, j = (int)r4.y;
        float w = __uint_as_float(r4.z);
        float lg[8];
        float mx = -1e30f;
#pragma unroll
        for (int m = 0; m < 8; ++m) {
            lg[m] = (float)xuh[(size_t)s * 8 + m] - (float)xuh[(size_t)j * 8 + m] + vc[m];
            mx = fmaxf(mx, lg[m]);
        }
        float den = 0.f;
#pragma unroll
        for (int m = 0; m < 8; ++m) {
            lg[m] = __expf(lg[m] - mx);
            den += lg[m];
        }
        float inv = w / den;
        float t = 0.f;
#pragma unroll
        for (int m = 0; m < 8; ++m) {
            float sum = 0.f;
            for (int c = 0; c < C_DIM; ++c) {
                HH x;
                x.u = (unsigned int)datah[(size_t)j * 64 + c];
                sum = fmaf((float)x.f2[0], var_w[((size_t)m * 64 + c) * 64 + lane], sum);
            }
            t = fmaf(lg[m] * inv, sum, t);
        }
        atomicAdd(&out[(size_t)s * 64 + lane], t);
    }
}

extern "C" void kernel_launch(void* const* d_in, const int* in_sizes, int n_in,
                              void* d_out, int out_size, void* d_ws, size_t ws_size,
                              hipStream_t stream) {
    const float* data  = (const float*)d_in[0];
    const int*   esrc  = (const int*)d_in[1];
    const int*   edst  = (const int*)d_in[2];
    const float* ew    = (const float*)d_in[3];
    const float* var_u = (const float*)d_in[4];
    const float* var_c = (const float*)d_in[5];
    const float* var_w = (const float*)d_in[6];
    const float* var_b = (const float*)d_in[7];
    float* out = (float*)d_out;

    int V = in_sizes[0] / C_DIM;
    int E = in_sizes[1];
    int nb = (V + 511) >> BSHIFT;  // 196 for V=100000 (<= NBMAX)

    char* ws = (char*)d_ws;
    size_t off = 0;
    auto alloc = [&](size_t bytes) -> void* {
        void* p = ws + off;
        off = (off + bytes + 255) & ~(size_t)255;
        return p;
    };
    // zero region: ovf_cnt only (single tiny memset)
    int* ovf_cnt = (int*)alloc(256);

    _Float16*  xuh   = (_Float16*)alloc((size_t)V * 8 * 2);
    uint4*     ovf   = (uint4*)alloc((size_t)OVF_CAP * 16);
    unsigned int* recs = (unsigned int*)alloc((size_t)V * KSLOT * 4);
    _Float16*  bfrag = (_Float16*)alloc((size_t)512 * 64 * 2);
    unsigned short* datah = (unsigned short*)alloc((size_t)V * 64 * 2);
    uint2*     pool  = (uint2*)alloc((size_t)nb * G1 * CAP_PB * 8);
    int*       gpb   = (int*)alloc((size_t)nb * G1 * 4);
    int*       counts = (int*)alloc((size_t)V * 4);

    hipMemsetAsync(ovf_cnt, 0, 256, stream);

    int streamb = (V + 31) >> 5;  // 32 vertices (= 2048 elems) per block
    int g1 = G1 + 16 + streamb;
    prep_kernel<<<g1, 256, 0, stream>>>(data, var_u, esrc, edst, ew, var_w,
                                        xuh, datah, pool, gpb, ovf_cnt, ovf,
                                        bfrag, V, E, nb);
    place_kernel<<<nb, 512, 0, stream>>>(pool, gpb, recs, counts, ovf_cnt, ovf, V);
    int ntiles = (V + 15) / 16;
    int fgrid = 256 * 7;  // persistent blocks: 7 resident/CU (22.5KB LDS)
    if (fgrid > ntiles) fgrid = ntiles;
    fused_kernel<<<fgrid, 256, 0, stream>>>(datah, recs, xuh, var_c,
                                            counts, bfrag, var_b, out, V, ntiles);
    cleanup_kernel<<<64, 256, 0, stream>>>(ovf_cnt, ovf, xuh, var_c, var_w,
                                           datah, out);
}

// Round 10
// 193.768 us; speedup vs baseline: 1.2315x; 1.2315x over previous
//
#include <hip/hip_runtime.h>
#include <hip/hip_bf16.h>
#include <hip/hip_fp16.h>

#define C_DIM 64
#define M_DIM 8
#define O_DIM 64
#define KSLOT 26
#define OVF_CAP 32768

// ---- bucketing parameters ----
#define G1 512      // pass-1 bucket blocks (each takes a contiguous E/G1 chunk)
#define BSHIFT 9    // 512 vertices per bucket
#define NBMAX 208   // max buckets (V <= 106496)
#define CAP_PB 24   // pool records per (bucket, block) private section (192B = 3 lines)

typedef _Float16 h8 __attribute__((ext_vector_type(8)));
typedef float f32x4 __attribute__((ext_vector_type(4)));

union HH { __half2 h2; unsigned int u; _Float16 f2[2]; };

__device__ __forceinline__ unsigned int packh2(float a, float b) {
    HH x;
    x.f2[0] = (_Float16)a;
    x.f2[1] = (_Float16)b;
    return x.u;
}
__device__ __forceinline__ int rfl(int x) { return __builtin_amdgcn_readfirstlane(x); }

// Pass 1 + streaming prep:
//  blocks [0, G1): bucket edges by src>>BSHIFT into private per-(bucket,block)
//                  pool sections (L2-resident scatter window per block).
//  blocks [G1, G1+16): repack var_w into MFMA B-fragment order.
//  blocks [G1+16, ...): MERGED data->f16 + xu (butterfly-reduced).
__global__ __launch_bounds__(256) void prep_kernel(
    const float* __restrict__ data, const float* __restrict__ u,
    const int* __restrict__ esrc, const int* __restrict__ edst,
    const float* __restrict__ ew, const float* __restrict__ w,
    _Float16* __restrict__ xuh, unsigned short* __restrict__ datah,
    uint2* __restrict__ pool, int* __restrict__ gpb,
    int* __restrict__ ovf_cnt, uint4* __restrict__ ovf,
    _Float16* __restrict__ bfrag, int V, int E, int nb) {
    __shared__ int fcnt[NBMAX];
    __shared__ float uS[576];  // var_u staged with stride 9 (bank-spread)
    int b = blockIdx.x, t = threadIdx.x;

    if (b < G1) {
        // ---------------- bucketing role ----------------
        for (int i = t; i < NBMAX; i += 256) fcnt[i] = 0;
        __syncthreads();
        int per = (E + G1 - 1) / G1;
        int eBeg = b * per;
        int eEnd = min(E, eBeg + per);
        for (int e = eBeg + t; e < eEnd; e += 256) {
            int s = esrc[e];
            int bk = s >> BSHIFT;
            uint2 rec;
            rec.x = (unsigned int)edst[e] | ((unsigned int)(s & 511) << 17);
            rec.y = __float_as_uint(ew[e]);
            int fr = atomicAdd(&fcnt[bk], 1);
            if (fr < CAP_PB) {
                pool[((size_t)bk * G1 + b) * CAP_PB + fr] = rec;
            } else {
                int oi = atomicAdd(ovf_cnt, 1);
                if (oi < OVF_CAP) {
                    uint4 o4;
                    o4.x = (unsigned int)s;
                    o4.y = rec.x & 0x1FFFFu;
                    o4.z = rec.y;
                    o4.w = 0;
                    ovf[oi] = o4;
                }
            }
        }
        __syncthreads();
        if (t < nb) {
            int fc = fcnt[t];
            gpb[t * G1 + b] = (fc < CAP_PB) ? fc : CAP_PB;
        }
        return;
    }

    if (b < G1 + 16) {
        // ---------------- wb fold role ----------------
        int tt = (b - G1) * 256 + t;
        int kt = tt >> 8;
        int rem = tt & 255;
        int nt = rem >> 6;
        int lane = rem & 63;
        int quad = lane >> 4;
        int n = nt * 16 + (lane & 15);
#pragma unroll
        for (int j = 0; j < 8; ++j) {
            int k = kt * 32 + quad * 8 + j;
            bfrag[(size_t)tt * 8 + j] = (_Float16)w[k * 64 + n];
        }
        return;
    }

    // ---------------- streaming role: data->f16 + fused xu ----------------
    int vb = b - (G1 + 16);
    for (int i = t; i < 512; i += 256) uS[(i >> 3) * 9 + (i & 7)] = u[i];
    __syncthreads();

    size_t base = (size_t)vb * 2048 + (size_t)t * 8;
    float x[8];
    if (base + 7 < (size_t)V * C_DIM) {
        f32x4 x0 = *(const f32x4*)&data[base];
        f32x4 x1 = *(const f32x4*)&data[base + 4];
        uint4 o;
        o.x = packh2(x0[0], x0[1]);
        o.y = packh2(x0[2], x0[3]);
        o.z = packh2(x1[0], x1[1]);
        o.w = packh2(x1[2], x1[3]);
        *(uint4*)&datah[base] = o;
        x[0] = x0[0]; x[1] = x0[1]; x[2] = x0[2]; x[3] = x0[3];
        x[4] = x1[0]; x[5] = x1[1]; x[6] = x1[2]; x[7] = x1[3];
    } else {
#pragma unroll
        for (int i = 0; i < 8; ++i) x[i] = 0.f;
    }
    // per-lane partials over this lane's 8 channels
    int c0 = (t & 7) * 8;
    float p[8];
#pragma unroll
    for (int m = 0; m < 8; ++m) p[m] = 0.f;
#pragma unroll
    for (int i = 0; i < 8; ++i) {
        const float* ur = &uS[(c0 + i) * 9];
#pragma unroll
        for (int m = 0; m < 8; ++m) p[m] = fmaf(x[i], ur[m], p[m]);
    }
    // butterfly-reduce across the 8 lanes of this vertex
#pragma unroll
    for (int d = 1; d < 8; d <<= 1) {
#pragma unroll
        for (int m = 0; m < 8; ++m) p[m] += __shfl_xor(p[m], d, 64);
    }
    int v = vb * 32 + (t >> 3);
    if (v < V) {
        int mi = t & 7;
        float outv = p[0];
#pragma unroll
        for (int m = 1; m < 8; ++m) if (mi == m) outv = p[m];
        xuh[(size_t)v * 8 + mi] = (_Float16)outv;
    }
}

// Pass 2: one block (512 threads) per 512-vertex bucket. Bulk-loads the whole
// 96KB pool slice into LDS (12 uint4 iters), then one thread per section ranks
// its ~12 records via LDS counters; 4B packed CSR records. Emits counts[].
__global__ __launch_bounds__(512) void place_kernel(
    const uint2* __restrict__ pool, const int* __restrict__ gpb,
    unsigned int* __restrict__ recs, int* __restrict__ counts,
    int* __restrict__ ovf_cnt, uint4* __restrict__ ovf, int V) {
    __shared__ uint2 lpool[G1 * CAP_PB];  // 512*24*8 = 96 KB
    __shared__ int vcnt[512];
    __shared__ int cnts[G1];
    int b = blockIdx.x, t = threadIdx.x;
    vcnt[t] = 0;
    cnts[t] = gpb[b * G1 + t];
    const uint4* src = (const uint4*)&pool[(size_t)b * G1 * CAP_PB];
    uint4* dst4 = (uint4*)lpool;
#pragma unroll
    for (int k = 0; k < G1 * CAP_PB / 2 / 512; ++k) {
        dst4[k * 512 + t] = src[k * 512 + t];
    }
    __syncthreads();

    {
        int cnt = cnts[t];
        if (cnt > CAP_PB) cnt = CAP_PB;
        if (cnt < 0) cnt = 0;
        int basei = t * CAP_PB;
        for (int k = 0; k < cnt; ++k) {
            uint2 rec = lpool[basei + k];
            int low = (int)(rec.x >> 17);
            int dst = (int)(rec.x & 0x1FFFFu);
            int r = atomicAdd(&vcnt[low], 1);
            int v = (b << BSHIFT) + low;
            if (r < KSLOT) {
                HH wh;
                wh.f2[0] = (_Float16)__uint_as_float(rec.y);
                unsigned int wf = wh.u & 0xFFFFu;  // sign bit 0 (w >= 0)
                recs[(size_t)v * KSLOT + r] = (unsigned int)dst | (wf << 17);
            } else {
                int oi = atomicAdd(ovf_cnt, 1);
                if (oi < OVF_CAP) {
                    uint4 o4;
                    o4.x = (unsigned int)v;
                    o4.y = (unsigned int)dst;
                    o4.z = rec.y;
                    o4.w = 0;
                    ovf[oi] = o4;
                }
            }
        }
    }
    __syncthreads();
    int v0 = (b << BSHIFT) + t;
    if (v0 < V) counts[v0] = vcnt[t] < KSLOT ? vcnt[t] : KSLOT;
}

// Fused (R8-verified main loop): per 16-vertex tile, 4 waves x 4 rows.
// Epilogue now atomicAdd (out is zeroed by harness; adds commute), and each
// block's tail grid-strides the overflow records exactly (cleanup folded in,
// one fewer kernel launch).
#define A_STRIDE 520
__global__ __launch_bounds__(256) void fused_kernel(
    const unsigned short* __restrict__ datah, const unsigned int* __restrict__ recs,
    const _Float16* __restrict__ xuh, const float* __restrict__ vc,
    const int* __restrict__ counts, const _Float16* __restrict__ bfragG,
    const float* __restrict__ bias, float* __restrict__ out, int V,
    const int* __restrict__ ovf_cnt, const uint4* __restrict__ ovf,
    const float* __restrict__ var_w) {
    __shared__ _Float16 At[16 * A_STRIDE];
    __shared__ int ebj[4][64];
    __shared__ uint4 ebq[4][64];
    __shared__ float xscS[4][4][8];
    __shared__ int pS[4][5];
    __shared__ int oS[4][4];
    int wave = rfl(threadIdx.x >> 6);
    int lane = threadIdx.x & 63;
    int v_base = blockIdx.x * 16;
    int v0 = v_base + wave * 4;

    if (lane < 4) {
        int v = v0 + lane;
        int dd = (v < V) ? min(counts[v], KSLOT) : 0;
        oS[wave][lane] = v * KSLOT;
        pS[wave][lane + 1] = dd;
    }
    if (lane == 0) {
        pS[wave][0] = 0;
        int s = 0;
#pragma unroll
        for (int i = 1; i <= 4; ++i) {
            s += pS[wave][i];
            pS[wave][i] = s;
        }
    }
    if (lane < 32) {
        int i = lane >> 3, m = lane & 7;
        int v = v0 + i;
        float s = 0.f;
        if (v < V) s = (float)xuh[(size_t)v0 * 8 + lane] + vc[m];
        xscS[wave][i][m] = s;
    }

    HH z; z.u = 0;
    __half2 acc[4][4];
#pragma unroll
    for (int i = 0; i < 4; ++i)
#pragma unroll
        for (int k = 0; k < 4; ++k) acc[i][k] = z.h2;

    int total = rfl(pS[wave][4]);

    for (int c0 = 0; c0 < total; c0 += 64) {
        // ---- Phase A: one edge per lane across the wave's 4 rows ----
        int g = c0 + lane;
        if (g < total) {
            int p1 = pS[wave][1], p2 = pS[wave][2], p3 = pS[wave][3];
            int r = (g >= p1) + (g >= p2) + (g >= p3);
            int pr = (r > 0) ? ((r > 1) ? ((r > 2) ? p3 : p2) : p1) : 0;
            int ob = oS[wave][r];
            int pos = ob + (g - pr);
            unsigned int rec = recs[pos];
            int j = (int)(rec & 0x1FFFFu);
            HH wh; wh.u = rec >> 17;
            float w = (float)wh.f2[0];
            f32x4 xa = *(const f32x4*)&xscS[wave][r][0];
            f32x4 xb = *(const f32x4*)&xscS[wave][r][4];
            uint4 xr = *(const uint4*)&xuh[(size_t)j * 8];
            HH a2, b2, c2, d2;
            a2.u = xr.x; b2.u = xr.y; c2.u = xr.z; d2.u = xr.w;
            float lg[8];
            lg[0] = xa[0] - (float)a2.f2[0];
            lg[1] = xa[1] - (float)a2.f2[1];
            lg[2] = xa[2] - (float)b2.f2[0];
            lg[3] = xa[3] - (float)b2.f2[1];
            lg[4] = xb[0] - (float)c2.f2[0];
            lg[5] = xb[1] - (float)c2.f2[1];
            lg[6] = xb[2] - (float)d2.f2[0];
            lg[7] = xb[3] - (float)d2.f2[1];
            float mx = -1e30f;
#pragma unroll
            for (int m = 0; m < 8; ++m) mx = fmaxf(mx, lg[m]);
            float den = 0.f;
#pragma unroll
            for (int m = 0; m < 8; ++m) {
                lg[m] = __expf(lg[m] - mx);
                den += lg[m];
            }
            float inv = w / den;
#pragma unroll
            for (int m = 0; m < 8; ++m) lg[m] *= inv;
            uint4 qp;
            qp.x = packh2(lg[0], lg[1]);
            qp.y = packh2(lg[2], lg[3]);
            qp.z = packh2(lg[4], lg[5]);
            qp.w = packh2(lg[6], lg[7]);
            ebj[wave][lane] = j;
            ebq[wave][lane] = qp;
        }
        // ---- Phase B: consume, row by row (same wave, 8-deep MLP) ----
#define CONSUME2(rr, qv, xsv)                                                  \
    do {                                                                       \
        HH q01, q23, q45, q67, xx;                                             \
        q01.u = (qv).x; q23.u = (qv).y;                                        \
        q45.u = (qv).z; q67.u = (qv).w;                                        \
        unsigned int xv_ = (unsigned int)(xsv);                                \
        xx.u = xv_ | (xv_ << 16);                                              \
        acc[rr][0] = __hfma2(xx.h2, q01.h2, acc[rr][0]);                       \
        acc[rr][1] = __hfma2(xx.h2, q23.h2, acc[rr][1]);                       \
        acc[rr][2] = __hfma2(xx.h2, q45.h2, acc[rr][2]);                       \
        acc[rr][3] = __hfma2(xx.h2, q67.h2, acc[rr][3]);                       \
    } while (0)
#pragma unroll
        for (int r2 = 0; r2 < 4; ++r2) {
            int pr0 = rfl(pS[wave][r2]);
            int pr1 = rfl(pS[wave][r2 + 1]);
            int lo2 = max(pr0, c0);
            int hi2 = min(pr1, c0 + 64);
            int n = hi2 - lo2;
            if (n <= 0) continue;
            int tb = lo2 - c0;
            int tt = 0;
            for (; tt + 8 <= n; tt += 8) {
                int jj[8];
                uint4 qq[8];
                unsigned short xs[8];
#pragma unroll
                for (int u = 0; u < 8; ++u) {
                    jj[u] = rfl(ebj[wave][tb + tt + u]);
                    qq[u] = ebq[wave][tb + tt + u];
                }
#pragma unroll
                for (int u = 0; u < 8; ++u) {
                    const unsigned short* xp = datah + ((size_t)jj[u] << 6);
                    xs[u] = xp[lane];
                }
#pragma unroll
                for (int u = 0; u < 8; ++u) CONSUME2(r2, qq[u], xs[u]);
            }
            for (; tt + 4 <= n; tt += 4) {
                int jj[4];
                uint4 qq[4];
                unsigned short xs[4];
#pragma unroll
                for (int u = 0; u < 4; ++u) {
                    jj[u] = rfl(ebj[wave][tb + tt + u]);
                    qq[u] = ebq[wave][tb + tt + u];
                }
#pragma unroll
                for (int u = 0; u < 4; ++u) {
                    const unsigned short* xp = datah + ((size_t)jj[u] << 6);
                    xs[u] = xp[lane];
                }
#pragma unroll
                for (int u = 0; u < 4; ++u) CONSUME2(r2, qq[u], xs[u]);
            }
            for (; tt < n; ++tt) {
                int j0 = rfl(ebj[wave][tb + tt]);
                uint4 qv = ebq[wave][tb + tt];
                const unsigned short* xp = datah + ((size_t)j0 << 6);
                unsigned short xs0 = xp[lane];
                CONSUME2(r2, qv, xs0);
            }
        }
    }

    // Deposit A-tile rows
#pragma unroll
    for (int i = 0; i < 4; ++i) {
        int row = wave * 4 + i;
        HH a01, a23, a45, a67;
        a01.h2 = acc[i][0]; a23.h2 = acc[i][1];
        a45.h2 = acc[i][2]; a67.h2 = acc[i][3];
        _Float16* Ar = &At[row * A_STRIDE + lane];
        Ar[0 * 64] = a01.f2[0];
        Ar[1 * 64] = a01.f2[1];
        Ar[2 * 64] = a23.f2[0];
        Ar[3 * 64] = a23.f2[1];
        Ar[4 * 64] = a45.f2[0];
        Ar[5 * 64] = a45.f2[1];
        Ar[6 * 64] = a67.f2[0];
        Ar[7 * 64] = a67.f2[1];
    }
    __syncthreads();

    // MFMA epilogue: wave = output column tile (atomicAdd: out zeroed by
    // harness; commutes with the overflow adds below)
    f32x4 cacc = {0.f, 0.f, 0.f, 0.f};
    int quad = lane >> 4;
    int r16 = lane & 15;
#pragma unroll
    for (int kt = 0; kt < 16; ++kt) {
        h8 a = *(const h8*)&At[r16 * A_STRIDE + kt * 32 + quad * 8];
        h8 b = *(const h8*)&bfragG[((size_t)(kt * 4 + wave) * 64 + lane) * 8];
        cacc = __builtin_amdgcn_mfma_f32_16x16x32_f16(a, b, cacc, 0, 0, 0);
    }
#pragma unroll
    for (int r = 0; r < 4; ++r) {
        int row = quad * 4 + r;
        int v = v_base + row;
        if (v < V) {
            int o = wave * 16 + r16;
            atomicAdd(&out[(size_t)v * 64 + o], cacc[r] + bias[o]);
        }
    }

    // ---- Folded overflow cleanup: exact f32 path, grid-strided by wave ----
    int n = min(*ovf_cnt, OVF_CAP);
    int nw = gridDim.x * 4;
    int wid = blockIdx.x * 4 + wave;
    for (int i = wid; i < n; i += nw) {
        uint4 r4 = ovf[i];
        int s = (int)r4.x, j = (int)r4.y;
        float w = __uint_as_float(r4.z);
        float lg[8];
        float mx = -1e30f;
#pragma unroll
        for (int m = 0; m < 8; ++m) {
            lg[m] = (float)xuh[(size_t)s * 8 + m] - (float)xuh[(size_t)j * 8 + m] + vc[m];
            mx = fmaxf(mx, lg[m]);
        }
        float den = 0.f;
#pragma unroll
        for (int m = 0; m < 8; ++m) {
            lg[m] = __expf(lg[m] - mx);
            den += lg[m];
        }
        float inv = w / den;
        float tacc = 0.f;
#pragma unroll
        for (int m = 0; m < 8; ++m) {
            float sum = 0.f;
            for (int c = 0; c < C_DIM; ++c) {
                HH x;
                x.u = (unsigned int)datah[(size_t)j * 64 + c];
                sum = fmaf((float)x.f2[0], var_w[((size_t)m * 64 + c) * 64 + lane], sum);
            }
            tacc = fmaf(lg[m] * inv, sum, tacc);
        }
        atomicAdd(&out[(size_t)s * 64 + lane], tacc);
    }
}

extern "C" void kernel_launch(void* const* d_in, const int* in_sizes, int n_in,
                              void* d_out, int out_size, void* d_ws, size_t ws_size,
                              hipStream_t stream) {
    const float* data  = (const float*)d_in[0];
    const int*   esrc  = (const int*)d_in[1];
    const int*   edst  = (const int*)d_in[2];
    const float* ew    = (const float*)d_in[3];
    const float* var_u = (const float*)d_in[4];
    const float* var_c = (const float*)d_in[5];
    const float* var_w = (const float*)d_in[6];
    const float* var_b = (const float*)d_in[7];
    float* out = (float*)d_out;

    int V = in_sizes[0] / C_DIM;
    int E = in_sizes[1];
    int nb = (V + 511) >> BSHIFT;  // 196 for V=100000 (<= NBMAX)

    char* ws = (char*)d_ws;
    size_t off = 0;
    auto alloc = [&](size_t bytes) -> void* {
        void* p = ws + off;
        off = (off + bytes + 255) & ~(size_t)255;
        return p;
    };
    // zero region: ovf_cnt only (single tiny memset)
    int* ovf_cnt = (int*)alloc(256);

    _Float16*  xuh   = (_Float16*)alloc((size_t)V * 8 * 2);
    uint4*     ovf   = (uint4*)alloc((size_t)OVF_CAP * 16);
    unsigned int* recs = (unsigned int*)alloc((size_t)V * KSLOT * 4);
    _Float16*  bfrag = (_Float16*)alloc((size_t)512 * 64 * 2);
    unsigned short* datah = (unsigned short*)alloc((size_t)V * 64 * 2);
    uint2*     pool  = (uint2*)alloc((size_t)nb * G1 * CAP_PB * 8);
    int*       gpb   = (int*)alloc((size_t)nb * G1 * 4);
    int*       counts = (int*)alloc((size_t)V * 4);

    hipMemsetAsync(ovf_cnt, 0, 256, stream);

    int streamb = (V + 31) >> 5;  // 32 vertices (= 2048 elems) per block
    int g1 = G1 + 16 + streamb;
    prep_kernel<<<g1, 256, 0, stream>>>(data, var_u, esrc, edst, ew, var_w,
                                        xuh, datah, pool, gpb, ovf_cnt, ovf,
                                        bfrag, V, E, nb);
    place_kernel<<<nb, 512, 0, stream>>>(pool, gpb, recs, counts, ovf_cnt, ovf, V);
    fused_kernel<<<(V + 15) / 16, 256, 0, stream>>>(datah, recs, xuh, var_c,
                                                    counts, bfrag, var_b, out, V,
                                                    ovf_cnt, ovf, var_w);
}

// Round 11
// 187.908 us; speedup vs baseline: 1.2699x; 1.0312x over previous
//
#include <hip/hip_runtime.h>
#include <hip/hip_bf16.h>
#include <hip/hip_fp16.h>

#define C_DIM 64
#define M_DIM 8
#define O_DIM 64
#define KSLOT 26
#define OVF_CAP 32768

// ---- bucketing parameters ----
#define G1 512      // pass-1 bucket blocks (each takes a contiguous E/G1 chunk)
#define BSHIFT 9    // 512 vertices per bucket
#define NBMAX 208   // max buckets (V <= 106496)
#define CAP_PB 24   // pool records per (bucket, block) private section (192B = 3 lines)

typedef _Float16 h8 __attribute__((ext_vector_type(8)));
typedef float f32x4 __attribute__((ext_vector_type(4)));

union HH { __half2 h2; unsigned int u; _Float16 f2[2]; };

__device__ __forceinline__ unsigned int packh2(float a, float b) {
    HH x;
    x.f2[0] = (_Float16)a;
    x.f2[1] = (_Float16)b;
    return x.u;
}
__device__ __forceinline__ int rfl(int x) { return __builtin_amdgcn_readfirstlane(x); }

// Pass 1 + streaming prep:
//  blocks [0, G1): bucket edges by src>>BSHIFT into private per-(bucket,block)
//                  pool sections (L2-resident scatter window per block).
//                  Overflow edges -> exact list + per-vertex ovfflag.
//  blocks [G1, G1+16): repack var_w into MFMA B-fragment order.
//  blocks [G1+16, ...): MERGED data->f16 + xu (butterfly-reduced).
__global__ __launch_bounds__(256) void prep_kernel(
    const float* __restrict__ data, const float* __restrict__ u,
    const int* __restrict__ esrc, const int* __restrict__ edst,
    const float* __restrict__ ew, const float* __restrict__ w,
    _Float16* __restrict__ xuh, unsigned short* __restrict__ datah,
    uint2* __restrict__ pool, int* __restrict__ gpb,
    int* __restrict__ ovf_cnt, uint4* __restrict__ ovf,
    unsigned char* __restrict__ ovfflag,
    _Float16* __restrict__ bfrag, int V, int E, int nb) {
    __shared__ int fcnt[NBMAX];
    __shared__ float uS[576];  // var_u staged with stride 9 (bank-spread)
    int b = blockIdx.x, t = threadIdx.x;

    if (b < G1) {
        // ---------------- bucketing role ----------------
        for (int i = t; i < NBMAX; i += 256) fcnt[i] = 0;
        __syncthreads();
        int per = (E + G1 - 1) / G1;
        int eBeg = b * per;
        int eEnd = min(E, eBeg + per);
        for (int e = eBeg + t; e < eEnd; e += 256) {
            int s = esrc[e];
            int bk = s >> BSHIFT;
            uint2 rec;
            rec.x = (unsigned int)edst[e] | ((unsigned int)(s & 511) << 17);
            rec.y = __float_as_uint(ew[e]);
            int fr = atomicAdd(&fcnt[bk], 1);
            if (fr < CAP_PB) {
                pool[((size_t)bk * G1 + b) * CAP_PB + fr] = rec;
            } else {
                ovfflag[s] = 1;
                int oi = atomicAdd(ovf_cnt, 1);
                if (oi < OVF_CAP) {
                    uint4 o4;
                    o4.x = (unsigned int)s;
                    o4.y = rec.x & 0x1FFFFu;
                    o4.z = rec.y;
                    o4.w = 0;
                    ovf[oi] = o4;
                }
            }
        }
        __syncthreads();
        if (t < nb) {
            int fc = fcnt[t];
            gpb[t * G1 + b] = (fc < CAP_PB) ? fc : CAP_PB;
        }
        return;
    }

    if (b < G1 + 16) {
        // ---------------- wb fold role ----------------
        int tt = (b - G1) * 256 + t;
        int kt = tt >> 8;
        int rem = tt & 255;
        int nt = rem >> 6;
        int lane = rem & 63;
        int quad = lane >> 4;
        int n = nt * 16 + (lane & 15);
#pragma unroll
        for (int j = 0; j < 8; ++j) {
            int k = kt * 32 + quad * 8 + j;
            bfrag[(size_t)tt * 8 + j] = (_Float16)w[k * 64 + n];
        }
        return;
    }

    // ---------------- streaming role: data->f16 + fused xu ----------------
    int vb = b - (G1 + 16);
    for (int i = t; i < 512; i += 256) uS[(i >> 3) * 9 + (i & 7)] = u[i];
    __syncthreads();

    size_t base = (size_t)vb * 2048 + (size_t)t * 8;
    float x[8];
    if (base + 7 < (size_t)V * C_DIM) {
        f32x4 x0 = *(const f32x4*)&data[base];
        f32x4 x1 = *(const f32x4*)&data[base + 4];
        uint4 o;
        o.x = packh2(x0[0], x0[1]);
        o.y = packh2(x0[2], x0[3]);
        o.z = packh2(x1[0], x1[1]);
        o.w = packh2(x1[2], x1[3]);
        *(uint4*)&datah[base] = o;
        x[0] = x0[0]; x[1] = x0[1]; x[2] = x0[2]; x[3] = x0[3];
        x[4] = x1[0]; x[5] = x1[1]; x[6] = x1[2]; x[7] = x1[3];
    } else {
#pragma unroll
        for (int i = 0; i < 8; ++i) x[i] = 0.f;
    }
    // per-lane partials over this lane's 8 channels
    int c0 = (t & 7) * 8;
    float p[8];
#pragma unroll
    for (int m = 0; m < 8; ++m) p[m] = 0.f;
#pragma unroll
    for (int i = 0; i < 8; ++i) {
        const float* ur = &uS[(c0 + i) * 9];
#pragma unroll
        for (int m = 0; m < 8; ++m) p[m] = fmaf(x[i], ur[m], p[m]);
    }
    // butterfly-reduce across the 8 lanes of this vertex
#pragma unroll
    for (int d = 1; d < 8; d <<= 1) {
#pragma unroll
        for (int m = 0; m < 8; ++m) p[m] += __shfl_xor(p[m], d, 64);
    }
    int v = vb * 32 + (t >> 3);
    if (v < V) {
        int mi = t & 7;
        float outv = p[0];
#pragma unroll
        for (int m = 1; m < 8; ++m) if (mi == m) outv = p[m];
        xuh[(size_t)v * 8 + mi] = (_Float16)outv;
    }
}

// Pass 2: one block (512 threads) per 512-vertex bucket. Bulk-loads the whole
// 96KB pool slice into LDS (12 uint4 iters), then one thread per section ranks
// its ~12 records via LDS counters; 4B packed CSR records. Emits counts[] and
// ovfflag[] for rank-overflow vertices.
__global__ __launch_bounds__(512) void place_kernel(
    const uint2* __restrict__ pool, const int* __restrict__ gpb,
    unsigned int* __restrict__ recs, int* __restrict__ counts,
    int* __restrict__ ovf_cnt, uint4* __restrict__ ovf,
    unsigned char* __restrict__ ovfflag, int V) {
    __shared__ uint2 lpool[G1 * CAP_PB];  // 512*24*8 = 96 KB
    __shared__ int vcnt[512];
    __shared__ int cnts[G1];
    int b = blockIdx.x, t = threadIdx.x;
    vcnt[t] = 0;
    cnts[t] = gpb[b * G1 + t];
    const uint4* src = (const uint4*)&pool[(size_t)b * G1 * CAP_PB];
    uint4* dst4 = (uint4*)lpool;
#pragma unroll
    for (int k = 0; k < G1 * CAP_PB / 2 / 512; ++k) {
        dst4[k * 512 + t] = src[k * 512 + t];
    }
    __syncthreads();

    {
        int cnt = cnts[t];
        if (cnt > CAP_PB) cnt = CAP_PB;
        if (cnt < 0) cnt = 0;
        int basei = t * CAP_PB;
        for (int k = 0; k < cnt; ++k) {
            uint2 rec = lpool[basei + k];
            int low = (int)(rec.x >> 17);
            int dst = (int)(rec.x & 0x1FFFFu);
            int r = atomicAdd(&vcnt[low], 1);
            int v = (b << BSHIFT) + low;
            if (r < KSLOT) {
                HH wh;
                wh.f2[0] = (_Float16)__uint_as_float(rec.y);
                unsigned int wf = wh.u & 0xFFFFu;  // sign bit 0 (w >= 0)
                recs[(size_t)v * KSLOT + r] = (unsigned int)dst | (wf << 17);
            } else {
                ovfflag[v] = 1;
                int oi = atomicAdd(ovf_cnt, 1);
                if (oi < OVF_CAP) {
                    uint4 o4;
                    o4.x = (unsigned int)v;
                    o4.y = (unsigned int)dst;
                    o4.z = rec.y;
                    o4.w = 0;
                    ovf[oi] = o4;
                }
            }
        }
    }
    __syncthreads();
    int v0 = (b << BSHIFT) + t;
    if (v0 < V) counts[v0] = vcnt[t] < KSLOT ? vcnt[t] : KSLOT;
}

// Fused (R8-verified main loop): per 16-vertex tile, 4 waves x 4 rows.
// Epilogue: plain store for normal vertices; atomicAdd only for the rare
// ovfflag'd vertices (commutes with the folded overflow adds; out pre-zeroed).
#define A_STRIDE 520
__global__ __launch_bounds__(256) void fused_kernel(
    const unsigned short* __restrict__ datah, const unsigned int* __restrict__ recs,
    const _Float16* __restrict__ xuh, const float* __restrict__ vc,
    const int* __restrict__ counts, const _Float16* __restrict__ bfragG,
    const float* __restrict__ bias, float* __restrict__ out, int V,
    const int* __restrict__ ovf_cnt, const uint4* __restrict__ ovf,
    const unsigned char* __restrict__ ovfflag,
    const float* __restrict__ var_w) {
    __shared__ _Float16 At[16 * A_STRIDE];
    __shared__ int ebj[4][64];
    __shared__ uint4 ebq[4][64];
    __shared__ float xscS[4][4][8];
    __shared__ int pS[4][5];
    __shared__ int oS[4][4];
    int wave = rfl(threadIdx.x >> 6);
    int lane = threadIdx.x & 63;
    int v_base = blockIdx.x * 16;
    int v0 = v_base + wave * 4;

    if (lane < 4) {
        int v = v0 + lane;
        int dd = (v < V) ? min(counts[v], KSLOT) : 0;
        oS[wave][lane] = v * KSLOT;
        pS[wave][lane + 1] = dd;
    }
    if (lane == 0) {
        pS[wave][0] = 0;
        int s = 0;
#pragma unroll
        for (int i = 1; i <= 4; ++i) {
            s += pS[wave][i];
            pS[wave][i] = s;
        }
    }
    if (lane < 32) {
        int i = lane >> 3, m = lane & 7;
        int v = v0 + i;
        float s = 0.f;
        if (v < V) s = (float)xuh[(size_t)v0 * 8 + lane] + vc[m];
        xscS[wave][i][m] = s;
    }

    HH z; z.u = 0;
    __half2 acc[4][4];
#pragma unroll
    for (int i = 0; i < 4; ++i)
#pragma unroll
        for (int k = 0; k < 4; ++k) acc[i][k] = z.h2;

    int total = rfl(pS[wave][4]);

    for (int c0 = 0; c0 < total; c0 += 64) {
        // ---- Phase A: one edge per lane across the wave's 4 rows ----
        int g = c0 + lane;
        if (g < total) {
            int p1 = pS[wave][1], p2 = pS[wave][2], p3 = pS[wave][3];
            int r = (g >= p1) + (g >= p2) + (g >= p3);
            int pr = (r > 0) ? ((r > 1) ? ((r > 2) ? p3 : p2) : p1) : 0;
            int ob = oS[wave][r];
            int pos = ob + (g - pr);
            unsigned int rec = recs[pos];
            int j = (int)(rec & 0x1FFFFu);
            HH wh; wh.u = rec >> 17;
            float w = (float)wh.f2[0];
            f32x4 xa = *(const f32x4*)&xscS[wave][r][0];
            f32x4 xb = *(const f32x4*)&xscS[wave][r][4];
            uint4 xr = *(const uint4*)&xuh[(size_t)j * 8];
            HH a2, b2, c2, d2;
            a2.u = xr.x; b2.u = xr.y; c2.u = xr.z; d2.u = xr.w;
            float lg[8];
            lg[0] = xa[0] - (float)a2.f2[0];
            lg[1] = xa[1] - (float)a2.f2[1];
            lg[2] = xa[2] - (float)b2.f2[0];
            lg[3] = xa[3] - (float)b2.f2[1];
            lg[4] = xb[0] - (float)c2.f2[0];
            lg[5] = xb[1] - (float)c2.f2[1];
            lg[6] = xb[2] - (float)d2.f2[0];
            lg[7] = xb[3] - (float)d2.f2[1];
            float mx = -1e30f;
#pragma unroll
            for (int m = 0; m < 8; ++m) mx = fmaxf(mx, lg[m]);
            float den = 0.f;
#pragma unroll
            for (int m = 0; m < 8; ++m) {
                lg[m] = __expf(lg[m] - mx);
                den += lg[m];
            }
            float inv = w / den;
#pragma unroll
            for (int m = 0; m < 8; ++m) lg[m] *= inv;
            uint4 qp;
            qp.x = packh2(lg[0], lg[1]);
            qp.y = packh2(lg[2], lg[3]);
            qp.z = packh2(lg[4], lg[5]);
            qp.w = packh2(lg[6], lg[7]);
            ebj[wave][lane] = j;
            ebq[wave][lane] = qp;
        }
        // ---- Phase B: consume, row by row (same wave, 8-deep MLP) ----
#define CONSUME2(rr, qv, xsv)                                                  \
    do {                                                                       \
        HH q01, q23, q45, q67, xx;                                             \
        q01.u = (qv).x; q23.u = (qv).y;                                        \
        q45.u = (qv).z; q67.u = (qv).w;                                        \
        unsigned int xv_ = (unsigned int)(xsv);                                \
        xx.u = xv_ | (xv_ << 16);                                              \
        acc[rr][0] = __hfma2(xx.h2, q01.h2, acc[rr][0]);                       \
        acc[rr][1] = __hfma2(xx.h2, q23.h2, acc[rr][1]);                       \
        acc[rr][2] = __hfma2(xx.h2, q45.h2, acc[rr][2]);                       \
        acc[rr][3] = __hfma2(xx.h2, q67.h2, acc[rr][3]);                       \
    } while (0)
#pragma unroll
        for (int r2 = 0; r2 < 4; ++r2) {
            int pr0 = rfl(pS[wave][r2]);
            int pr1 = rfl(pS[wave][r2 + 1]);
            int lo2 = max(pr0, c0);
            int hi2 = min(pr1, c0 + 64);
            int n = hi2 - lo2;
            if (n <= 0) continue;
            int tb = lo2 - c0;
            int tt = 0;
            for (; tt + 8 <= n; tt += 8) {
                int jj[8];
                uint4 qq[8];
                unsigned short xs[8];
#pragma unroll
                for (int u = 0; u < 8; ++u) {
                    jj[u] = rfl(ebj[wave][tb + tt + u]);
                    qq[u] = ebq[wave][tb + tt + u];
                }
#pragma unroll
                for (int u = 0; u < 8; ++u) {
                    const unsigned short* xp = datah + ((size_t)jj[u] << 6);
                    xs[u] = xp[lane];
                }
#pragma unroll
                for (int u = 0; u < 8; ++u) CONSUME2(r2, qq[u], xs[u]);
            }
            for (; tt + 4 <= n; tt += 4) {
                int jj[4];
                uint4 qq[4];
                unsigned short xs[4];
#pragma unroll
                for (int u = 0; u < 4; ++u) {
                    jj[u] = rfl(ebj[wave][tb + tt + u]);
                    qq[u] = ebq[wave][tb + tt + u];
                }
#pragma unroll
                for (int u = 0; u < 4; ++u) {
                    const unsigned short* xp = datah + ((size_t)jj[u] << 6);
                    xs[u] = xp[lane];
                }
#pragma unroll
                for (int u = 0; u < 4; ++u) CONSUME2(r2, qq[u], xs[u]);
            }
            for (; tt < n; ++tt) {
                int j0 = rfl(ebj[wave][tb + tt]);
                uint4 qv = ebq[wave][tb + tt];
                const unsigned short* xp = datah + ((size_t)j0 << 6);
                unsigned short xs0 = xp[lane];
                CONSUME2(r2, qv, xs0);
            }
        }
    }

    // Deposit A-tile rows
#pragma unroll
    for (int i = 0; i < 4; ++i) {
        int row = wave * 4 + i;
        HH a01, a23, a45, a67;
        a01.h2 = acc[i][0]; a23.h2 = acc[i][1];
        a45.h2 = acc[i][2]; a67.h2 = acc[i][3];
        _Float16* Ar = &At[row * A_STRIDE + lane];
        Ar[0 * 64] = a01.f2[0];
        Ar[1 * 64] = a01.f2[1];
        Ar[2 * 64] = a23.f2[0];
        Ar[3 * 64] = a23.f2[1];
        Ar[4 * 64] = a45.f2[0];
        Ar[5 * 64] = a45.f2[1];
        Ar[6 * 64] = a67.f2[0];
        Ar[7 * 64] = a67.f2[1];
    }
    __syncthreads();

    // MFMA epilogue: wave = output column tile. Plain store unless the vertex
    // is overflow-flagged (then atomicAdd, commuting with the tail below).
    f32x4 cacc = {0.f, 0.f, 0.f, 0.f};
    int quad = lane >> 4;
    int r16 = lane & 15;
#pragma unroll
    for (int kt = 0; kt < 16; ++kt) {
        h8 a = *(const h8*)&At[r16 * A_STRIDE + kt * 32 + quad * 8];
        h8 b = *(const h8*)&bfragG[((size_t)(kt * 4 + wave) * 64 + lane) * 8];
        cacc = __builtin_amdgcn_mfma_f32_16x16x32_f16(a, b, cacc, 0, 0, 0);
    }
#pragma unroll
    for (int r = 0; r < 4; ++r) {
        int row = quad * 4 + r;
        int v = v_base + row;
        if (v < V) {
            int o = wave * 16 + r16;
            float val = cacc[r] + bias[o];
            if (ovfflag[v]) {
                atomicAdd(&out[(size_t)v * 64 + o], val);
            } else {
                out[(size_t)v * 64 + o] = val;
            }
        }
    }

    // ---- Folded overflow cleanup: exact f32 path, grid-strided by wave ----
    int n = min(*ovf_cnt, OVF_CAP);
    int nw = gridDim.x * 4;
    int wid = blockIdx.x * 4 + wave;
    for (int i = wid; i < n; i += nw) {
        uint4 r4 = ovf[i];
        int s = (int)r4.x, j = (int)r4.y;
        float w = __uint_as_float(r4.z);
        float lg[8];
        float mx = -1e30f;
#pragma unroll
        for (int m = 0; m < 8; ++m) {
            lg[m] = (float)xuh[(size_t)s * 8 + m] - (float)xuh[(size_t)j * 8 + m] + vc[m];
            mx = fmaxf(mx, lg[m]);
        }
        float den = 0.f;
#pragma unroll
        for (int m = 0; m < 8; ++m) {
            lg[m] = __expf(lg[m] - mx);
            den += lg[m];
        }
        float inv = w / den;
        float tacc = 0.f;
#pragma unroll
        for (int m = 0; m < 8; ++m) {
            float sum = 0.f;
            for (int c = 0; c < C_DIM; ++c) {
                HH x;
                x.u = (unsigned int)datah[(size_t)j * 64 + c];
                sum = fmaf((float)x.f2[0], var_w[((size_t)m * 64 + c) * 64 + lane], sum);
            }
            tacc = fmaf(lg[m] * inv, sum, tacc);
        }
        atomicAdd(&out[(size_t)s * 64 + lane], tacc);
    }
}

extern "C" void kernel_launch(void* const* d_in, const int* in_sizes, int n_in,
                              void* d_out, int out_size, void* d_ws, size_t ws_size,
                              hipStream_t stream) {
    const float* data  = (const float*)d_in[0];
    const int*   esrc  = (const int*)d_in[1];
    const int*   edst  = (const int*)d_in[2];
    const float* ew    = (const float*)d_in[3];
    const float* var_u = (const float*)d_in[4];
    const float* var_c = (const float*)d_in[5];
    const float* var_w = (const float*)d_in[6];
    const float* var_b = (const float*)d_in[7];
    float* out = (float*)d_out;

    int V = in_sizes[0] / C_DIM;
    int E = in_sizes[1];
    int nb = (V + 511) >> BSHIFT;  // 196 for V=100000 (<= NBMAX)

    char* ws = (char*)d_ws;
    size_t off = 0;
    auto alloc = [&](size_t bytes) -> void* {
        void* p = ws + off;
        off = (off + bytes + 255) & ~(size_t)255;
        return p;
    };
    // zero region: ovf_cnt (256B) + ovfflag (V bytes) -- single memset
    size_t zbytes = 256 + (size_t)V;
    char* zr = (char*)alloc(zbytes);
    int* ovf_cnt = (int*)zr;
    unsigned char* ovfflag = (unsigned char*)(zr + 256);

    _Float16*  xuh   = (_Float16*)alloc((size_t)V * 8 * 2);
    uint4*     ovf   = (uint4*)alloc((size_t)OVF_CAP * 16);
    unsigned int* recs = (unsigned int*)alloc((size_t)V * KSLOT * 4);
    _Float16*  bfrag = (_Float16*)alloc((size_t)512 * 64 * 2);
    unsigned short* datah = (unsigned short*)alloc((size_t)V * 64 * 2);
    uint2*     pool  = (uint2*)alloc((size_t)nb * G1 * CAP_PB * 8);
    int*       gpb   = (int*)alloc((size_t)nb * G1 * 4);
    int*       counts = (int*)alloc((size_t)V * 4);

    hipMemsetAsync(zr, 0, zbytes, stream);

    int streamb = (V + 31) >> 5;  // 32 vertices (= 2048 elems) per block
    int g1 = G1 + 16 + streamb;
    prep_kernel<<<g1, 256, 0, stream>>>(data, var_u, esrc, edst, ew, var_w,
                                        xuh, datah, pool, gpb, ovf_cnt, ovf,
                                        ovfflag, bfrag, V, E, nb);
    place_kernel<<<nb, 512, 0, stream>>>(pool, gpb, recs, counts, ovf_cnt, ovf,
                                         ovfflag, V);
    fused_kernel<<<(V + 15) / 16, 256, 0, stream>>>(datah, recs, xuh, var_c,
                                                    counts, bfrag, var_b, out, V,
                                                    ovf_cnt, ovf, ovfflag, var_w);
}

// Round 12
// 187.790 us; speedup vs baseline: 1.2707x; 1.0006x over previous
//
#include <hip/hip_runtime.h>
#include <hip/hip_bf16.h>
#include <hip/hip_fp16.h>

#define C_DIM 64
#define M_DIM 8
#define O_DIM 64
#define KSLOT 26
#define OVF_CAP 32768

// ---- bucketing parameters ----
#define G1 512      // pass-1 bucket blocks (each takes a contiguous E/G1 chunk)
#define BSHIFT 9    // 512 vertices per bucket
#define NBMAX 208   // max buckets (V <= 106496)
#define CAP_PB 24   // pool records per (bucket, block) private section (192B = 3 lines)

typedef _Float16 h8 __attribute__((ext_vector_type(8)));
typedef float f32x4 __attribute__((ext_vector_type(4)));

union HH { __half2 h2; unsigned int u; _Float16 f2[2]; };

__device__ __forceinline__ unsigned int packh2(float a, float b) {
    HH x;
    x.f2[0] = (_Float16)a;
    x.f2[1] = (_Float16)b;
    return x.u;
}
__device__ __forceinline__ int rfl(int x) { return __builtin_amdgcn_readfirstlane(x); }

// Pass 1 + streaming prep:
//  blocks [0, G1): bucket edges by src>>BSHIFT into private per-(bucket,block)
//                  pool sections (L2-resident scatter window per block).
//                  Overflow edges -> exact list + per-vertex ovfflag.
//  blocks [G1, G1+16): repack var_w into MFMA B-fragment order.
//  blocks [G1+16, ...): MERGED data->f16 + xu (butterfly-reduced) + ej=exp(-xu).
__global__ __launch_bounds__(256) void prep_kernel(
    const float* __restrict__ data, const float* __restrict__ u,
    const int* __restrict__ esrc, const int* __restrict__ edst,
    const float* __restrict__ ew, const float* __restrict__ w,
    _Float16* __restrict__ xuh, _Float16* __restrict__ ejh,
    unsigned short* __restrict__ datah,
    uint2* __restrict__ pool, int* __restrict__ gpb,
    int* __restrict__ ovf_cnt, uint4* __restrict__ ovf,
    unsigned char* __restrict__ ovfflag,
    _Float16* __restrict__ bfrag, int V, int E, int nb) {
    __shared__ int fcnt[NBMAX];
    __shared__ float uS[576];  // var_u staged with stride 9 (bank-spread)
    int b = blockIdx.x, t = threadIdx.x;

    if (b < G1) {
        // ---------------- bucketing role ----------------
        for (int i = t; i < NBMAX; i += 256) fcnt[i] = 0;
        __syncthreads();
        int per = (E + G1 - 1) / G1;
        int eBeg = b * per;
        int eEnd = min(E, eBeg + per);
        for (int e = eBeg + t; e < eEnd; e += 256) {
            int s = esrc[e];
            int bk = s >> BSHIFT;
            uint2 rec;
            rec.x = (unsigned int)edst[e] | ((unsigned int)(s & 511) << 17);
            rec.y = __float_as_uint(ew[e]);
            int fr = atomicAdd(&fcnt[bk], 1);
            if (fr < CAP_PB) {
                pool[((size_t)bk * G1 + b) * CAP_PB + fr] = rec;
            } else {
                ovfflag[s] = 1;
                int oi = atomicAdd(ovf_cnt, 1);
                if (oi < OVF_CAP) {
                    uint4 o4;
                    o4.x = (unsigned int)s;
                    o4.y = rec.x & 0x1FFFFu;
                    o4.z = rec.y;
                    o4.w = 0;
                    ovf[oi] = o4;
                }
            }
        }
        __syncthreads();
        if (t < nb) {
            int fc = fcnt[t];
            gpb[t * G1 + b] = (fc < CAP_PB) ? fc : CAP_PB;
        }
        return;
    }

    if (b < G1 + 16) {
        // ---------------- wb fold role ----------------
        int tt = (b - G1) * 256 + t;
        int kt = tt >> 8;
        int rem = tt & 255;
        int nt = rem >> 6;
        int lane = rem & 63;
        int quad = lane >> 4;
        int n = nt * 16 + (lane & 15);
#pragma unroll
        for (int j = 0; j < 8; ++j) {
            int k = kt * 32 + quad * 8 + j;
            bfrag[(size_t)tt * 8 + j] = (_Float16)w[k * 64 + n];
        }
        return;
    }

    // ---------------- streaming role: data->f16 + fused xu + ej ----------------
    int vb = b - (G1 + 16);
    for (int i = t; i < 512; i += 256) uS[(i >> 3) * 9 + (i & 7)] = u[i];
    __syncthreads();

    size_t base = (size_t)vb * 2048 + (size_t)t * 8;
    float x[8];
    if (base + 7 < (size_t)V * C_DIM) {
        f32x4 x0 = *(const f32x4*)&data[base];
        f32x4 x1 = *(const f32x4*)&data[base + 4];
        uint4 o;
        o.x = packh2(x0[0], x0[1]);
        o.y = packh2(x0[2], x0[3]);
        o.z = packh2(x1[0], x1[1]);
        o.w = packh2(x1[2], x1[3]);
        *(uint4*)&datah[base] = o;
        x[0] = x0[0]; x[1] = x0[1]; x[2] = x0[2]; x[3] = x0[3];
        x[4] = x1[0]; x[5] = x1[1]; x[6] = x1[2]; x[7] = x1[3];
    } else {
#pragma unroll
        for (int i = 0; i < 8; ++i) x[i] = 0.f;
    }
    // per-lane partials over this lane's 8 channels
    int c0 = (t & 7) * 8;
    float p[8];
#pragma unroll
    for (int m = 0; m < 8; ++m) p[m] = 0.f;
#pragma unroll
    for (int i = 0; i < 8; ++i) {
        const float* ur = &uS[(c0 + i) * 9];
#pragma unroll
        for (int m = 0; m < 8; ++m) p[m] = fmaf(x[i], ur[m], p[m]);
    }
    // butterfly-reduce across the 8 lanes of this vertex
#pragma unroll
    for (int d = 1; d < 8; d <<= 1) {
#pragma unroll
        for (int m = 0; m < 8; ++m) p[m] += __shfl_xor(p[m], d, 64);
    }
    int v = vb * 32 + (t >> 3);
    if (v < V) {
        int mi = t & 7;
        float outv = p[0];
#pragma unroll
        for (int m = 1; m < 8; ++m) if (mi == m) outv = p[m];
        xuh[(size_t)v * 8 + mi] = (_Float16)outv;
        ejh[(size_t)v * 8 + mi] = (_Float16)__expf(-outv);
    }
}

// Pass 2 (unchanged): one block (512 threads) per 512-vertex bucket.
__global__ __launch_bounds__(512) void place_kernel(
    const uint2* __restrict__ pool, const int* __restrict__ gpb,
    unsigned int* __restrict__ recs, int* __restrict__ counts,
    int* __restrict__ ovf_cnt, uint4* __restrict__ ovf,
    unsigned char* __restrict__ ovfflag, int V) {
    __shared__ uint2 lpool[G1 * CAP_PB];  // 512*24*8 = 96 KB
    __shared__ int vcnt[512];
    __shared__ int cnts[G1];
    int b = blockIdx.x, t = threadIdx.x;
    vcnt[t] = 0;
    cnts[t] = gpb[b * G1 + t];
    const uint4* src = (const uint4*)&pool[(size_t)b * G1 * CAP_PB];
    uint4* dst4 = (uint4*)lpool;
#pragma unroll
    for (int k = 0; k < G1 * CAP_PB / 2 / 512; ++k) {
        dst4[k * 512 + t] = src[k * 512 + t];
    }
    __syncthreads();

    {
        int cnt = cnts[t];
        if (cnt > CAP_PB) cnt = CAP_PB;
        if (cnt < 0) cnt = 0;
        int basei = t * CAP_PB;
        for (int k = 0; k < cnt; ++k) {
            uint2 rec = lpool[basei + k];
            int low = (int)(rec.x >> 17);
            int dst = (int)(rec.x & 0x1FFFFu);
            int r = atomicAdd(&vcnt[low], 1);
            int v = (b << BSHIFT) + low;
            if (r < KSLOT) {
                HH wh;
                wh.f2[0] = (_Float16)__uint_as_float(rec.y);
                unsigned int wf = wh.u & 0xFFFFu;  // sign bit 0 (w >= 0)
                recs[(size_t)v * KSLOT + r] = (unsigned int)dst | (wf << 17);
            } else {
                ovfflag[v] = 1;
                int oi = atomicAdd(ovf_cnt, 1);
                if (oi < OVF_CAP) {
                    uint4 o4;
                    o4.x = (unsigned int)v;
                    o4.y = (unsigned int)dst;
                    o4.z = rec.y;
                    o4.w = 0;
                    ovf[oi] = o4;
                }
            }
        }
    }
    __syncthreads();
    int v0 = (b << BSHIFT) + t;
    if (v0 < V) counts[v0] = vcnt[t] < KSLOT ? vcnt[t] : KSLOT;
}

// Fused: per 16-vertex tile, 4 waves x 4 rows. Phase A uses the factored
// softmax: q_m = es[m]*ej[m]/sum (es = exp(xu_s+c) per row, ej = exp(-xu_j)
// gathered f16x8) -- no per-edge exp/max chain. Epilogue: plain store unless
// overflow-flagged (then atomicAdd); folded exact overflow tail.
#define A_STRIDE 520
__global__ __launch_bounds__(256) void fused_kernel(
    const unsigned short* __restrict__ datah, const unsigned int* __restrict__ recs,
    const _Float16* __restrict__ xuh, const _Float16* __restrict__ ejh,
    const float* __restrict__ vc,
    const int* __restrict__ counts, const _Float16* __restrict__ bfragG,
    const float* __restrict__ bias, float* __restrict__ out, int V,
    const int* __restrict__ ovf_cnt, const uint4* __restrict__ ovf,
    const unsigned char* __restrict__ ovfflag,
    const float* __restrict__ var_w) {
    __shared__ _Float16 At[16 * A_STRIDE];
    __shared__ int ebj[4][64];
    __shared__ uint4 ebq[4][64];
    __shared__ float xscS[4][4][8];
    __shared__ int pS[4][5];
    __shared__ int oS[4][4];
    int wave = rfl(threadIdx.x >> 6);
    int lane = threadIdx.x & 63;
    int v_base = blockIdx.x * 16;
    int v0 = v_base + wave * 4;

    if (lane < 4) {
        int v = v0 + lane;
        int dd = (v < V) ? min(counts[v], KSLOT) : 0;
        oS[wave][lane] = v * KSLOT;
        pS[wave][lane + 1] = dd;
    }
    if (lane == 0) {
        pS[wave][0] = 0;
        int s = 0;
#pragma unroll
        for (int i = 1; i <= 4; ++i) {
            s += pS[wave][i];
            pS[wave][i] = s;
        }
    }
    if (lane < 32) {
        int i = lane >> 3, m = lane & 7;
        int v = v0 + i;
        float s = 0.f;
        if (v < V) s = __expf((float)xuh[(size_t)v0 * 8 + lane] + vc[m]);
        xscS[wave][i][m] = s;
    }

    HH z; z.u = 0;
    __half2 acc[4][4];
#pragma unroll
    for (int i = 0; i < 4; ++i)
#pragma unroll
        for (int k = 0; k < 4; ++k) acc[i][k] = z.h2;

    int total = rfl(pS[wave][4]);

    for (int c0 = 0; c0 < total; c0 += 64) {
        // ---- Phase A: one edge per lane across the wave's 4 rows ----
        int g = c0 + lane;
        if (g < total) {
            int p1 = pS[wave][1], p2 = pS[wave][2], p3 = pS[wave][3];
            int r = (g >= p1) + (g >= p2) + (g >= p3);
            int pr = (r > 0) ? ((r > 1) ? ((r > 2) ? p3 : p2) : p1) : 0;
            int ob = oS[wave][r];
            int pos = ob + (g - pr);
            unsigned int rec = recs[pos];
            int j = (int)(rec & 0x1FFFFu);
            HH wh; wh.u = rec >> 17;
            float w = (float)wh.f2[0];
            f32x4 xa = *(const f32x4*)&xscS[wave][r][0];
            f32x4 xb = *(const f32x4*)&xscS[wave][r][4];
            uint4 xr = *(const uint4*)&ejh[(size_t)j * 8];
            HH a2, b2, c2, d2;
            a2.u = xr.x; b2.u = xr.y; c2.u = xr.z; d2.u = xr.w;
            float lg[8];
            lg[0] = xa[0] * (float)a2.f2[0];
            lg[1] = xa[1] * (float)a2.f2[1];
            lg[2] = xa[2] * (float)b2.f2[0];
            lg[3] = xa[3] * (float)b2.f2[1];
            lg[4] = xb[0] * (float)c2.f2[0];
            lg[5] = xb[1] * (float)c2.f2[1];
            lg[6] = xb[2] * (float)d2.f2[0];
            lg[7] = xb[3] * (float)d2.f2[1];
            float den = (lg[0] + lg[1]) + (lg[2] + lg[3]) +
                        ((lg[4] + lg[5]) + (lg[6] + lg[7]));
            float inv = w / den;
#pragma unroll
            for (int m = 0; m < 8; ++m) lg[m] *= inv;
            uint4 qp;
            qp.x = packh2(lg[0], lg[1]);
            qp.y = packh2(lg[2], lg[3]);
            qp.z = packh2(lg[4], lg[5]);
            qp.w = packh2(lg[6], lg[7]);
            ebj[wave][lane] = j;
            ebq[wave][lane] = qp;
        }
        // ---- Phase B: consume, row by row (same wave, 8-deep MLP) ----
#define CONSUME2(rr, qv, xsv)                                                  \
    do {                                                                       \
        HH q01, q23, q45, q67, xx;                                             \
        q01.u = (qv).x; q23.u = (qv).y;                                        \
        q45.u = (qv).z; q67.u = (qv).w;                                        \
        unsigned int xv_ = (unsigned int)(xsv);                                \
        xx.u = xv_ | (xv_ << 16);                                              \
        acc[rr][0] = __hfma2(xx.h2, q01.h2, acc[rr][0]);                       \
        acc[rr][1] = __hfma2(xx.h2, q23.h2, acc[rr][1]);                       \
        acc[rr][2] = __hfma2(xx.h2, q45.h2, acc[rr][2]);                       \
        acc[rr][3] = __hfma2(xx.h2, q67.h2, acc[rr][3]);                       \
    } while (0)
#pragma unroll
        for (int r2 = 0; r2 < 4; ++r2) {
            int pr0 = rfl(pS[wave][r2]);
            int pr1 = rfl(pS[wave][r2 + 1]);
            int lo2 = max(pr0, c0);
            int hi2 = min(pr1, c0 + 64);
            int n = hi2 - lo2;
            if (n <= 0) continue;
            int tb = lo2 - c0;
            int tt = 0;
            for (; tt + 8 <= n; tt += 8) {
                int jj[8];
                uint4 qq[8];
                unsigned short xs[8];
#pragma unroll
                for (int u = 0; u < 8; ++u) {
                    jj[u] = rfl(ebj[wave][tb + tt + u]);
                    qq[u] = ebq[wave][tb + tt + u];
                }
#pragma unroll
                for (int u = 0; u < 8; ++u) {
                    const unsigned short* xp = datah + ((size_t)jj[u] << 6);
                    xs[u] = xp[lane];
                }
#pragma unroll
                for (int u = 0; u < 8; ++u) CONSUME2(r2, qq[u], xs[u]);
            }
            for (; tt + 4 <= n; tt += 4) {
                int jj[4];
                uint4 qq[4];
                unsigned short xs[4];
#pragma unroll
                for (int u = 0; u < 4; ++u) {
                    jj[u] = rfl(ebj[wave][tb + tt + u]);
                    qq[u] = ebq[wave][tb + tt + u];
                }
#pragma unroll
                for (int u = 0; u < 4; ++u) {
                    const unsigned short* xp = datah + ((size_t)jj[u] << 6);
                    xs[u] = xp[lane];
                }
#pragma unroll
                for (int u = 0; u < 4; ++u) CONSUME2(r2, qq[u], xs[u]);
            }
            for (; tt < n; ++tt) {
                int j0 = rfl(ebj[wave][tb + tt]);
                uint4 qv = ebq[wave][tb + tt];
                const unsigned short* xp = datah + ((size_t)j0 << 6);
                unsigned short xs0 = xp[lane];
                CONSUME2(r2, qv, xs0);
            }
        }
    }

    // Deposit A-tile rows
#pragma unroll
    for (int i = 0; i < 4; ++i) {
        int row = wave * 4 + i;
        HH a01, a23, a45, a67;
        a01.h2 = acc[i][0]; a23.h2 = acc[i][1];
        a45.h2 = acc[i][2]; a67.h2 = acc[i][3];
        _Float16* Ar = &At[row * A_STRIDE + lane];
        Ar[0 * 64] = a01.f2[0];
        Ar[1 * 64] = a01.f2[1];
        Ar[2 * 64] = a23.f2[0];
        Ar[3 * 64] = a23.f2[1];
        Ar[4 * 64] = a45.f2[0];
        Ar[5 * 64] = a45.f2[1];
        Ar[6 * 64] = a67.f2[0];
        Ar[7 * 64] = a67.f2[1];
    }
    __syncthreads();

    // MFMA epilogue: wave = output column tile. Plain store unless the vertex
    // is overflow-flagged (then atomicAdd, commuting with the tail below).
    f32x4 cacc = {0.f, 0.f, 0.f, 0.f};
    int quad = lane >> 4;
    int r16 = lane & 15;
#pragma unroll
    for (int kt = 0; kt < 16; ++kt) {
        h8 a = *(const h8*)&At[r16 * A_STRIDE + kt * 32 + quad * 8];
        h8 b = *(const h8*)&bfragG[((size_t)(kt * 4 + wave) * 64 + lane) * 8];
        cacc = __builtin_amdgcn_mfma_f32_16x16x32_f16(a, b, cacc, 0, 0, 0);
    }
#pragma unroll
    for (int r = 0; r < 4; ++r) {
        int row = quad * 4 + r;
        int v = v_base + row;
        if (v < V) {
            int o = wave * 16 + r16;
            float val = cacc[r] + bias[o];
            if (ovfflag[v]) {
                atomicAdd(&out[(size_t)v * 64 + o], val);
            } else {
                out[(size_t)v * 64 + o] = val;
            }
        }
    }

    // ---- Folded overflow cleanup: exact f32 path (uses xuh), by wave ----
    int n = min(*ovf_cnt, OVF_CAP);
    int nw = gridDim.x * 4;
    int wid = blockIdx.x * 4 + wave;
    for (int i = wid; i < n; i += nw) {
        uint4 r4 = ovf[i];
        int s = (int)r4.x, j = (int)r4.y;
        float w = __uint_as_float(r4.z);
        float lg[8];
        float mx = -1e30f;
#pragma unroll
        for (int m = 0; m < 8; ++m) {
            lg[m] = (float)xuh[(size_t)s * 8 + m] - (float)xuh[(size_t)j * 8 + m] + vc[m];
            mx = fmaxf(mx, lg[m]);
        }
        float den = 0.f;
#pragma unroll
        for (int m = 0; m < 8; ++m) {
            lg[m] = __expf(lg[m] - mx);
            den += lg[m];
        }
        float inv = w / den;
        float tacc = 0.f;
#pragma unroll
        for (int m = 0; m < 8; ++m) {
            float sum = 0.f;
            for (int c = 0; c < C_DIM; ++c) {
                HH x;
                x.u = (unsigned int)datah[(size_t)j * 64 + c];
                sum = fmaf((float)x.f2[0], var_w[((size_t)m * 64 + c) * 64 + lane], sum);
            }
            tacc = fmaf(lg[m] * inv, sum, tacc);
        }
        atomicAdd(&out[(size_t)s * 64 + lane], tacc);
    }
}

extern "C" void kernel_launch(void* const* d_in, const int* in_sizes, int n_in,
                              void* d_out, int out_size, void* d_ws, size_t ws_size,
                              hipStream_t stream) {
    const float* data  = (const float*)d_in[0];
    const int*   esrc  = (const int*)d_in[1];
    const int*   edst  = (const int*)d_in[2];
    const float* ew    = (const float*)d_in[3];
    const float* var_u = (const float*)d_in[4];
    const float* var_c = (const float*)d_in[5];
    const float* var_w = (const float*)d_in[6];
    const float* var_b = (const float*)d_in[7];
    float* out = (float*)d_out;

    int V = in_sizes[0] / C_DIM;
    int E = in_sizes[1];
    int nb = (V + 511) >> BSHIFT;  // 196 for V=100000 (<= NBMAX)

    char* ws = (char*)d_ws;
    size_t off = 0;
    auto alloc = [&](size_t bytes) -> void* {
        void* p = ws + off;
        off = (off + bytes + 255) & ~(size_t)255;
        return p;
    };
    // zero region: ovf_cnt (256B) + ovfflag (V bytes) -- single memset
    size_t zbytes = 256 + (size_t)V;
    char* zr = (char*)alloc(zbytes);
    int* ovf_cnt = (int*)zr;
    unsigned char* ovfflag = (unsigned char*)(zr + 256);

    _Float16*  xuh   = (_Float16*)alloc((size_t)V * 8 * 2);
    _Float16*  ejh   = (_Float16*)alloc((size_t)V * 8 * 2);
    uint4*     ovf   = (uint4*)alloc((size_t)OVF_CAP * 16);
    unsigned int* recs = (unsigned int*)alloc((size_t)V * KSLOT * 4);
    _Float16*  bfrag = (_Float16*)alloc((size_t)512 * 64 * 2);
    unsigned short* datah = (unsigned short*)alloc((size_t)V * 64 * 2);
    uint2*     pool  = (uint2*)alloc((size_t)nb * G1 * CAP_PB * 8);
    int*       gpb   = (int*)alloc((size_t)nb * G1 * 4);
    int*       counts = (int*)alloc((size_t)V * 4);

    hipMemsetAsync(zr, 0, zbytes, stream);

    int streamb = (V + 31) >> 5;  // 32 vertices (= 2048 elems) per block
    int g1 = G1 + 16 + streamb;
    prep_kernel<<<g1, 256, 0, stream>>>(data, var_u, esrc, edst, ew, var_w,
                                        xuh, ejh, datah, pool, gpb, ovf_cnt, ovf,
                                        ovfflag, bfrag, V, E, nb);
    place_kernel<<<nb, 512, 0, stream>>>(pool, gpb, recs, counts, ovf_cnt, ovf,
                                         ovfflag, V);
    fused_kernel<<<(V + 15) / 16, 256, 0, stream>>>(datah, recs, xuh, ejh, var_c,
                                                    counts, bfrag, var_b, out, V,
                                                    ovf_cnt, ovf, ovfflag, var_w);
}